// Round 9
// baseline (298.593 us; speedup 1.0000x reference)
//
#include <hip/hip_runtime.h>

#define N_NODES 10000
#define E_EDGES 640000
#define IN_CH   512
#define OUT_CH  256
#define CSR_CAP (E_EDGES + 8 * N_NODES + 64)    // x8-padded capacity + prefetch slack
#define G_GEMM_X 157                            // ceil(10000/64)
#define G_GEMM  (G_GEMM_X * 2)                  // x2 column halves
#define G_SCAT  625                             // 625*256*4 = 640000 edges

typedef short bf16x8 __attribute__((ext_vector_type(8)));
typedef float f32x4  __attribute__((ext_vector_type(4)));

__device__ __forceinline__ unsigned short f2b(float f) {
    unsigned int u = __float_as_uint(f);
    return (unsigned short)((u + 0x7FFFu + ((u >> 16) & 1u)) >> 16);
}

// ---------------- degree histogram + CSR sentinel prefill ----------------
__global__ void deg_kernel(const int* __restrict__ row, int* __restrict__ deg,
                           int* __restrict__ csr_col, int E) {
    int e = blockIdx.x * blockDim.x + threadIdx.x;
    if (e < E) atomicAdd(&deg[row[e]], 1);
    int stride = gridDim.x * blockDim.x;
    for (int i = e; i < CSR_CAP; i += stride) csr_col[i] = N_NODES;  // sentinel -> zero row
}

// ---------------- scan: padded exclusive offsets (deg rounded up to x8) + dinv ----------------
__global__ void scan_kernel(const int* __restrict__ deg, int* __restrict__ offs,
                            float* __restrict__ dinv, int n) {
    __shared__ int partial[256];
    int tid = threadIdx.x;
    int per = (n + 255) / 256;
    int start = tid * per;
    int end = start + per; if (end > n) end = n; if (start > n) start = n;
    int s = 0;
    for (int i = start; i < end; i++) {
        int d = deg[i];
        dinv[i] = (d > 0) ? rsqrtf((float)d) : 0.0f;
        s += (d + 7) & ~7;
    }
    partial[tid] = s;
    __syncthreads();
    for (int off = 1; off < 256; off <<= 1) {
        int v = (tid >= off) ? partial[tid - off] : 0;
        __syncthreads();
        partial[tid] += v;
        __syncthreads();
    }
    int base = (tid == 0) ? 0 : partial[tid - 1];
    for (int i = start; i < end; i++) {
        offs[i] = base;
        base += (deg[i] + 7) & ~7;
    }
    if (tid == 255) offs[n] = partial[255];
}

// ---------------- fused GEMM (blocks 0..G_GEMM-1) + edge scatter (rest) ----------------
// GEMM: h0[m][c] = sum_k x[m][k]*w[c][k] + b[c]; fp32 full rows + bf16 interleaved rows
// pre-scaled by dinv[m]. bf16 buffer is [(N+1)][256]; row N is the zero pad row.
// Scatter: csr_col[offs[r] + cursor[r]++] = c  (4B payload, nontemporal store).
__global__ __launch_bounds__(256) void gemm_scatter(const float* __restrict__ x,
                                                    const float* __restrict__ w,
                                                    const float* __restrict__ bias,
                                                    const float* __restrict__ dinv,
                                                    float* __restrict__ h0,
                                                    unsigned short* __restrict__ h0b,
                                                    const int* __restrict__ row,
                                                    const int* __restrict__ col,
                                                    const int* __restrict__ offs,
                                                    int* __restrict__ cursor,
                                                    int* __restrict__ csr_col) {
    __shared__ unsigned short As[64][72];
    __shared__ unsigned short Bs[128][72];
    int bid = blockIdx.x;
    int tid = threadIdx.x;
    if (bid >= G_GEMM) {
        // ---- scatter path ----
        int idx = (bid - G_GEMM) * 256 + tid;
        #pragma unroll
        for (int it = 0; it < 4; it++) {
            int e = idx + it * (G_SCAT * 256);
            if (e < E_EDGES) {
                int r = row[e];
                int c = col[e];
                int p = offs[r] + atomicAdd(&cursor[r], 1);
                __builtin_nontemporal_store(c, &csr_col[p]);
            }
        }
        return;
    }
    // ---- gemm path ----
    int bx = bid % G_GEMM_X;
    int plane = bid / G_GEMM_X;
    int wave = tid >> 6, lane = tid & 63, quad = lane >> 4, l16 = lane & 15;
    int row0 = bx * 64;
    int n0 = plane * 128;

    int ar = tid >> 2;
    int aseg = (tid & 3) * 16;
    int br = tid >> 1;
    int bseg = (tid & 1) * 32;

    f32x4 acc[8] = {};
    for (int k0 = 0; k0 < IN_CH; k0 += 64) {
        {
            int gr = row0 + ar;
            if (gr < N_NODES) {
                const float4* src = (const float4*)(x + (size_t)gr * IN_CH + k0 + aseg);
                #pragma unroll
                for (int i = 0; i < 4; i++) {
                    float4 v = src[i];
                    ushort4 o;
                    o.x = f2b(v.x); o.y = f2b(v.y); o.z = f2b(v.z); o.w = f2b(v.w);
                    *(ushort4*)&As[ar][aseg + i * 4] = o;
                }
            } else {
                ushort4 z = {0, 0, 0, 0};
                #pragma unroll
                for (int i = 0; i < 4; i++) *(ushort4*)&As[ar][aseg + i * 4] = z;
            }
        }
        {
            const float4* src = (const float4*)(w + (size_t)(n0 + br) * IN_CH + k0 + bseg);
            #pragma unroll
            for (int i = 0; i < 8; i++) {
                float4 v = src[i];
                ushort4 o;
                o.x = f2b(v.x); o.y = f2b(v.y); o.z = f2b(v.z); o.w = f2b(v.w);
                *(ushort4*)&Bs[br][bseg + i * 4] = o;
            }
        }
        __syncthreads();
        #pragma unroll
        for (int kk = 0; kk < 2; kk++) {
            bf16x8 a = *(const bf16x8*)&As[wave * 16 + l16][kk * 32 + quad * 8];
            #pragma unroll
            for (int t = 0; t < 8; t++) {
                bf16x8 b = *(const bf16x8*)&Bs[t * 16 + l16][kk * 32 + quad * 8];
                acc[t] = __builtin_amdgcn_mfma_f32_16x16x32_bf16(a, b, acc[t], 0, 0, 0);
            }
        }
        __syncthreads();
    }
    #pragma unroll
    for (int t = 0; t < 8; t++) {
        int col_ = n0 + t * 16 + l16;
        float bv = bias[col_];
        #pragma unroll
        for (int r = 0; r < 4; r++) {
            int grow = row0 + wave * 16 + quad * 4 + r;
            if (grow < N_NODES) {
                float v = acc[t][r] + bv;
                h0 [(size_t)grow * OUT_CH + col_] = v;
                h0b[(size_t)grow * OUT_CH + col_] = f2b(v * dinv[grow]);
            }
        }
    }
    // zero the pad row (sentinel gather target) — one block does it
    if (bx == 0 && plane == 0 && tid < 128)
        ((unsigned int*)(h0b + (size_t)N_NODES * OUT_CH))[tid] = 0u;
}

// ---------------- SpMM: one wave per node, full-row 8B gathers, 8 edges in flight ------
// hb is [(n+1)][256] bf16 pre-scaled by dinv[row]; lane owns channels [4*lane, 4*lane+4).
// y = dinv[node] * sum(hb[col_e]); bf16 outputs pre-scaled by dinv[node] for next hop.
__global__ __launch_bounds__(256) void spmm_kernel(const unsigned short* __restrict__ hb,
                                                   const int* __restrict__ offs,
                                                   const int* __restrict__ csr_col,
                                                   const float* __restrict__ dinv,
                                                   const float* __restrict__ prev,
                                                   const float* __restrict__ wts, int widx,
                                                   unsigned short* __restrict__ yb_out,
                                                   float* __restrict__ axpy_out,
                                                   unsigned short* __restrict__ axpyb_out,
                                                   int n) {
    int node = (blockIdx.x * blockDim.x + threadIdx.x) >> 6;
    int lane = threadIdx.x & 63;
    if (node >= n) return;

    int s = offs[node], e = offs[node + 1];   // 8-aligned
    float a0 = 0.f, a1 = 0.f, a2 = 0.f, a3 = 0.f;
    if (s < e) {
        int4 m0 = *(const int4*)(csr_col + s);
        int4 m1 = *(const int4*)(csr_col + s + 4);
        int p = s;
        while (true) {
            int pn = p + 8;
            int4 x0 = *(const int4*)(csr_col + pn);       // prefetch (slack-safe)
            int4 x1 = *(const int4*)(csr_col + pn + 4);
            uint2 v0 = *(const uint2*)(hb + (size_t)m0.x * OUT_CH + 4 * lane);
            uint2 v1 = *(const uint2*)(hb + (size_t)m0.y * OUT_CH + 4 * lane);
            uint2 v2 = *(const uint2*)(hb + (size_t)m0.z * OUT_CH + 4 * lane);
            uint2 v3 = *(const uint2*)(hb + (size_t)m0.w * OUT_CH + 4 * lane);
            uint2 v4 = *(const uint2*)(hb + (size_t)m1.x * OUT_CH + 4 * lane);
            uint2 v5 = *(const uint2*)(hb + (size_t)m1.y * OUT_CH + 4 * lane);
            uint2 v6 = *(const uint2*)(hb + (size_t)m1.z * OUT_CH + 4 * lane);
            uint2 v7 = *(const uint2*)(hb + (size_t)m1.w * OUT_CH + 4 * lane);
            a0 += __uint_as_float(v0.x << 16) + __uint_as_float(v1.x << 16)
                + __uint_as_float(v2.x << 16) + __uint_as_float(v3.x << 16)
                + __uint_as_float(v4.x << 16) + __uint_as_float(v5.x << 16)
                + __uint_as_float(v6.x << 16) + __uint_as_float(v7.x << 16);
            a1 += __uint_as_float(v0.x & 0xFFFF0000u) + __uint_as_float(v1.x & 0xFFFF0000u)
                + __uint_as_float(v2.x & 0xFFFF0000u) + __uint_as_float(v3.x & 0xFFFF0000u)
                + __uint_as_float(v4.x & 0xFFFF0000u) + __uint_as_float(v5.x & 0xFFFF0000u)
                + __uint_as_float(v6.x & 0xFFFF0000u) + __uint_as_float(v7.x & 0xFFFF0000u);
            a2 += __uint_as_float(v0.y << 16) + __uint_as_float(v1.y << 16)
                + __uint_as_float(v2.y << 16) + __uint_as_float(v3.y << 16)
                + __uint_as_float(v4.y << 16) + __uint_as_float(v5.y << 16)
                + __uint_as_float(v6.y << 16) + __uint_as_float(v7.y << 16);
            a3 += __uint_as_float(v0.y & 0xFFFF0000u) + __uint_as_float(v1.y & 0xFFFF0000u)
                + __uint_as_float(v2.y & 0xFFFF0000u) + __uint_as_float(v3.y & 0xFFFF0000u)
                + __uint_as_float(v4.y & 0xFFFF0000u) + __uint_as_float(v5.y & 0xFFFF0000u)
                + __uint_as_float(v6.y & 0xFFFF0000u) + __uint_as_float(v7.y & 0xFFFF0000u);
            m0 = x0; m1 = x1; p = pn;
            if (p >= e) break;
        }
    }

    float di = dinv[node];
    float y0 = di * a0, y1 = di * a1, y2 = di * a2, y3 = di * a3;

    size_t base = (size_t)node * OUT_CH + 4 * lane;
    size_t padrow = (size_t)n * OUT_CH + 4 * lane;
    if (yb_out) {
        ushort4 o;
        o.x = f2b(di * y0); o.y = f2b(di * y1); o.z = f2b(di * y2); o.w = f2b(di * y3);
        *(ushort4*)(yb_out + base) = o;
        if (node == 0) { ushort4 z = {0, 0, 0, 0}; *(ushort4*)(yb_out + padrow) = z; }
    }
    if (axpy_out || axpyb_out) {
        float wk = wts[widx];
        float4 pv = *(const float4*)(prev + base);
        float4 o;
        o.x = pv.x + wk * y0;
        o.y = pv.y + wk * y1;
        o.z = pv.z + wk * y2;
        o.w = pv.w + wk * y3;
        if (axpy_out) *(float4*)(axpy_out + base) = o;
        if (axpyb_out) {
            ushort4 ob;
            ob.x = f2b(di * o.x); ob.y = f2b(di * o.y);
            ob.z = f2b(di * o.z); ob.w = f2b(di * o.w);
            *(ushort4*)(axpyb_out + base) = ob;
            if (node == 0) { ushort4 z = {0, 0, 0, 0}; *(ushort4*)(axpyb_out + padrow) = z; }
        }
    }
}

extern "C" void kernel_launch(void* const* d_in, const int* in_sizes, int n_in,
                              void* d_out, int out_size, void* d_ws, size_t ws_size,
                              hipStream_t stream) {
    const float* x     = (const float*)d_in[0];
    const int*   ei    = (const int*)d_in[1];   // [2, E]
    const float* lin_w = (const float*)d_in[2]; // [OUT_CH, IN_CH]
    const float* lin_b = (const float*)d_in[3]; // [OUT_CH]
    const float* wts   = (const float*)d_in[4]; // [K]
    float* out = (float*)d_out;

    char* ws = (char*)d_ws;
    size_t off = 0;
    auto alloc = [&](size_t bytes) -> void* {
        void* p = ws + off;
        off += (bytes + 255) & ~(size_t)255;
        return p;
    };
    int*   deg      = (int*)  alloc(N_NODES * 4 * 2); // deg + cursor (one memset)
    int*   cursor   = deg + N_NODES;
    int*   offs     = (int*)  alloc((N_NODES + 1) * 4);
    float* dinv     = (float*)alloc(N_NODES * 4);
    int*   csr_col  = (int*)  alloc((size_t)CSR_CAP * 4);
    float*          h0    = (float*)         alloc((size_t)N_NODES * OUT_CH * 4);
    unsigned short* h0b   = (unsigned short*)alloc((size_t)(N_NODES + 1) * OUT_CH * 2);
    float*          out1  = (float*)         alloc((size_t)N_NODES * OUT_CH * 4);
    unsigned short* out1b = (unsigned short*)alloc((size_t)(N_NODES + 1) * OUT_CH * 2);
    unsigned short* t2b   = (unsigned short*)alloc((size_t)(N_NODES + 1) * OUT_CH * 2);

    hipMemsetAsync(deg, 0, N_NODES * 4 * 2, stream);

    const int* row = ei;
    const int* col = ei + E_EDGES;

    deg_kernel<<<(E_EDGES + 255) / 256, 256, 0, stream>>>(row, deg, csr_col, E_EDGES);
    scan_kernel<<<1, 256, 0, stream>>>(deg, offs, dinv, N_NODES);

    // fused: GEMM (h0 fp32 + h0b bf16 pre-scaled) || CSR scatter
    gemm_scatter<<<G_GEMM + G_SCAT, 256, 0, stream>>>(x, lin_w, lin_b, dinv, h0, h0b,
                                                      row, col, offs, cursor, csr_col);

    int sgrid = (N_NODES + 3) / 4; // 1 wave/node, 4 waves/block
    // out1 = h0 + w0 * spmm(h0)
    spmm_kernel<<<sgrid, 256, 0, stream>>>(h0b, offs, csr_col, dinv, h0, wts, 0,
                                           nullptr, out1, out1b, N_NODES);
    // t2 = spmm(out1)
    spmm_kernel<<<sgrid, 256, 0, stream>>>(out1b, offs, csr_col, dinv, nullptr, wts, 0,
                                           t2b, nullptr, nullptr, N_NODES);
    // out = out1 + w1 * spmm(t2)
    spmm_kernel<<<sgrid, 256, 0, stream>>>(t2b, offs, csr_col, dinv, out1, wts, 1,
                                           nullptr, out, nullptr, N_NODES);
}

// Round 10
// 258.514 us; speedup vs baseline: 1.1550x; 1.1550x over previous
//
#include <hip/hip_runtime.h>

#define N_NODES 10000
#define E_EDGES 640000
#define IN_CH   512
#define OUT_CH  256
#define HALF_CH 128
#define CSR_CAP (E_EDGES + 16 * N_NODES + 128)  // padded capacity + prefetch slack
#define G_GEMM_X 157                            // ceil(10000/64)
#define G_GEMM  (G_GEMM_X * 2)                  // x2 planes
#define G_SCAT  625                             // 625*256*4 = 640000 edges

typedef short bf16x8 __attribute__((ext_vector_type(8)));
typedef float f32x4  __attribute__((ext_vector_type(4)));

__device__ __forceinline__ unsigned short f2b(float f) {
    unsigned int u = __float_as_uint(f);
    return (unsigned short)((u + 0x7FFFu + ((u >> 16) & 1u)) >> 16);
}

// ---------------- degree histogram (pure) ----------------
__global__ void deg_kernel(const int* __restrict__ row, int* __restrict__ deg, int E) {
    int e = blockIdx.x * blockDim.x + threadIdx.x;
    if (e < E) atomicAdd(&deg[row[e]], 1);
}

// ---------------- order-free segment allocation + dinv + pad-slot sentinels ----------------
// seg_start[i] = atomicAdd(counter, (deg[i]+15)&~15). CSR segments in arbitrary order —
// SpMM only needs [start, start+padded) per node. Pad slots get sentinel N_NODES (zero row).
__global__ void alloc_kernel(const int* __restrict__ deg, int* __restrict__ seg_start,
                             float* __restrict__ dinv, int* __restrict__ counter,
                             int* __restrict__ csr_col, int n) {
    int i = blockIdx.x * blockDim.x + threadIdx.x;
    if (i >= n) return;
    int d = deg[i];
    dinv[i] = (d > 0) ? rsqrtf((float)d) : 0.0f;
    int pad = (d + 15) & ~15;
    int s = atomicAdd(counter, pad);
    seg_start[i] = s;
    for (int j = d; j < pad; j++) csr_col[s + j] = N_NODES;
}

// ---------------- fused GEMM (blocks 0..G_GEMM-1) + edge scatter (rest) ----------------
// GEMM: h0[m][c] = sum_k x[m][k]*w[c][k] + b[c]; fp32 full rows + bf16 planar pre-scaled
// by dinv[m]. Planar bf16 buffers are [(N+1)][128] per plane; row N is the zero pad row.
// Scatter: csr_col[seg_start[r] + cursor[r]++] = c  (4B payload, norm-free CSR).
__global__ __launch_bounds__(256) void gemm_scatter(const float* __restrict__ x,
                                                    const float* __restrict__ w,
                                                    const float* __restrict__ bias,
                                                    const float* __restrict__ dinv,
                                                    float* __restrict__ h0,
                                                    unsigned short* __restrict__ h0b,
                                                    const int* __restrict__ row,
                                                    const int* __restrict__ col,
                                                    const int* __restrict__ seg_start,
                                                    int* __restrict__ cursor,
                                                    int* __restrict__ csr_col) {
    __shared__ unsigned short As[64][72];
    __shared__ unsigned short Bs[128][72];
    int bid = blockIdx.x;
    int tid = threadIdx.x;
    if (bid >= G_GEMM) {
        // ---- scatter path ----
        int idx = (bid - G_GEMM) * 256 + tid;
        #pragma unroll
        for (int it = 0; it < 4; it++) {
            int e = idx + it * (G_SCAT * 256);
            if (e < E_EDGES) {
                int r = row[e];
                int c = col[e];
                int p = seg_start[r] + atomicAdd(&cursor[r], 1);
                csr_col[p] = c;
            }
        }
        return;
    }
    // ---- gemm path ----
    int bx = bid % G_GEMM_X;
    int plane = bid / G_GEMM_X;
    int wave = tid >> 6, lane = tid & 63, quad = lane >> 4, l16 = lane & 15;
    int row0 = bx * 64;
    int n0 = plane * 128;
    unsigned short* h0b_p = h0b + (size_t)plane * (N_NODES + 1) * HALF_CH;

    int ar = tid >> 2;
    int aseg = (tid & 3) * 16;
    int br = tid >> 1;
    int bseg = (tid & 1) * 32;

    f32x4 acc[8] = {};
    for (int k0 = 0; k0 < IN_CH; k0 += 64) {
        {
            int gr = row0 + ar;
            if (gr < N_NODES) {
                const float4* src = (const float4*)(x + (size_t)gr * IN_CH + k0 + aseg);
                #pragma unroll
                for (int i = 0; i < 4; i++) {
                    float4 v = src[i];
                    ushort4 o;
                    o.x = f2b(v.x); o.y = f2b(v.y); o.z = f2b(v.z); o.w = f2b(v.w);
                    *(ushort4*)&As[ar][aseg + i * 4] = o;
                }
            } else {
                ushort4 z = {0, 0, 0, 0};
                #pragma unroll
                for (int i = 0; i < 4; i++) *(ushort4*)&As[ar][aseg + i * 4] = z;
            }
        }
        {
            const float4* src = (const float4*)(w + (size_t)(n0 + br) * IN_CH + k0 + bseg);
            #pragma unroll
            for (int i = 0; i < 8; i++) {
                float4 v = src[i];
                ushort4 o;
                o.x = f2b(v.x); o.y = f2b(v.y); o.z = f2b(v.z); o.w = f2b(v.w);
                *(ushort4*)&Bs[br][bseg + i * 4] = o;
            }
        }
        __syncthreads();
        #pragma unroll
        for (int kk = 0; kk < 2; kk++) {
            bf16x8 a = *(const bf16x8*)&As[wave * 16 + l16][kk * 32 + quad * 8];
            #pragma unroll
            for (int t = 0; t < 8; t++) {
                bf16x8 b = *(const bf16x8*)&Bs[t * 16 + l16][kk * 32 + quad * 8];
                acc[t] = __builtin_amdgcn_mfma_f32_16x16x32_bf16(a, b, acc[t], 0, 0, 0);
            }
        }
        __syncthreads();
    }
    #pragma unroll
    for (int t = 0; t < 8; t++) {
        int lcol = t * 16 + l16;
        int col_ = n0 + lcol;
        float bv = bias[col_];
        #pragma unroll
        for (int r = 0; r < 4; r++) {
            int grow = row0 + wave * 16 + quad * 4 + r;
            if (grow < N_NODES) {
                float v = acc[t][r] + bv;
                h0   [(size_t)grow * OUT_CH + col_] = v;
                h0b_p[(size_t)grow * HALF_CH + lcol] = f2b(v * dinv[grow]);
            }
        }
    }
    // zero the pad row (sentinel gather target) — one block per plane
    if (bx == 0 && tid < 64)
        ((unsigned int*)(h0b_p + (size_t)N_NODES * HALF_CH))[tid] = 0u;
}

// ---------------- SpMM: 16 edges in flight, 4 independent accumulator pairs ----------
// 2 waves per node (one per 128-ch plane). x16-padded segments (sentinels -> zero row).
// y = dinv[node] * sum(hb[col_e]); bf16 outputs pre-scaled by dinv[node] for next hop.
__global__ __launch_bounds__(256) void spmm_kernel(const unsigned short* __restrict__ hb,
                                                   const int* __restrict__ seg_start,
                                                   const int* __restrict__ deg,
                                                   const int* __restrict__ csr_col,
                                                   const float* __restrict__ dinv,
                                                   const float* __restrict__ prev,
                                                   const float* __restrict__ wts, int widx,
                                                   unsigned short* __restrict__ yb_out,
                                                   float* __restrict__ axpy_out,
                                                   unsigned short* __restrict__ axpyb_out,
                                                   int n) {
    int W = (blockIdx.x * blockDim.x + threadIdx.x) >> 6;
    int lane = threadIdx.x & 63;
    int plane = (W >= n) ? 1 : 0;
    int node = W - plane * n;
    if (node >= n) return;
    size_t pstride = (size_t)(n + 1) * HALF_CH;
    const unsigned short* hp = hb + (size_t)plane * pstride;

    int s = seg_start[node];
    int e = s + ((deg[node] + 15) & ~15);
    float lo[4] = {0.f, 0.f, 0.f, 0.f};
    float hi[4] = {0.f, 0.f, 0.f, 0.f};
    if (s < e) {
        int4 m0 = *(const int4*)(csr_col + s);
        int4 m1 = *(const int4*)(csr_col + s + 4);
        int4 m2 = *(const int4*)(csr_col + s + 8);
        int4 m3 = *(const int4*)(csr_col + s + 12);
        int p = s;
        while (true) {
            int pn = p + 16;
            int4 x0 = *(const int4*)(csr_col + pn);       // prefetch (slack-safe)
            int4 x1 = *(const int4*)(csr_col + pn + 4);
            int4 x2 = *(const int4*)(csr_col + pn + 8);
            int4 x3 = *(const int4*)(csr_col + pn + 12);
            unsigned int v[16];
            v[0]  = ((const unsigned int*)(hp + (size_t)m0.x * HALF_CH))[lane];
            v[1]  = ((const unsigned int*)(hp + (size_t)m0.y * HALF_CH))[lane];
            v[2]  = ((const unsigned int*)(hp + (size_t)m0.z * HALF_CH))[lane];
            v[3]  = ((const unsigned int*)(hp + (size_t)m0.w * HALF_CH))[lane];
            v[4]  = ((const unsigned int*)(hp + (size_t)m1.x * HALF_CH))[lane];
            v[5]  = ((const unsigned int*)(hp + (size_t)m1.y * HALF_CH))[lane];
            v[6]  = ((const unsigned int*)(hp + (size_t)m1.z * HALF_CH))[lane];
            v[7]  = ((const unsigned int*)(hp + (size_t)m1.w * HALF_CH))[lane];
            v[8]  = ((const unsigned int*)(hp + (size_t)m2.x * HALF_CH))[lane];
            v[9]  = ((const unsigned int*)(hp + (size_t)m2.y * HALF_CH))[lane];
            v[10] = ((const unsigned int*)(hp + (size_t)m2.z * HALF_CH))[lane];
            v[11] = ((const unsigned int*)(hp + (size_t)m2.w * HALF_CH))[lane];
            v[12] = ((const unsigned int*)(hp + (size_t)m3.x * HALF_CH))[lane];
            v[13] = ((const unsigned int*)(hp + (size_t)m3.y * HALF_CH))[lane];
            v[14] = ((const unsigned int*)(hp + (size_t)m3.z * HALF_CH))[lane];
            v[15] = ((const unsigned int*)(hp + (size_t)m3.w * HALF_CH))[lane];
            #pragma unroll
            for (int i = 0; i < 16; i++) {
                lo[i & 3] += __uint_as_float(v[i] << 16);
                hi[i & 3] += __uint_as_float(v[i] & 0xFFFF0000u);
            }
            m0 = x0; m1 = x1; m2 = x2; m3 = x3; p = pn;
            if (p >= e) break;
        }
    }
    float a0 = (lo[0] + lo[1]) + (lo[2] + lo[3]);
    float a1 = (hi[0] + hi[1]) + (hi[2] + hi[3]);

    float di = dinv[node];
    float y0 = di * a0, y1 = di * a1;

    size_t pbase = (size_t)plane * pstride + (size_t)node * HALF_CH + 2 * lane;
    size_t padrow = (size_t)plane * pstride + (size_t)n * HALF_CH + 2 * lane;
    if (yb_out) {
        ushort2 o; o.x = f2b(di * y0); o.y = f2b(di * y1);
        *(ushort2*)(yb_out + pbase) = o;
        if (node == 0) { ushort2 z = {0, 0}; *(ushort2*)(yb_out + padrow) = z; }
    }
    if (axpy_out || axpyb_out) {
        float wk = wts[widx];
        size_t fbase = (size_t)node * OUT_CH + plane * HALF_CH + 2 * lane;
        float2 pv = *(const float2*)(prev + fbase);
        float2 o;
        o.x = pv.x + wk * y0;
        o.y = pv.y + wk * y1;
        if (axpy_out) *(float2*)(axpy_out + fbase) = o;
        if (axpyb_out) {
            ushort2 ob; ob.x = f2b(di * o.x); ob.y = f2b(di * o.y);
            *(ushort2*)(axpyb_out + pbase) = ob;
            if (node == 0) { ushort2 z = {0, 0}; *(ushort2*)(axpyb_out + padrow) = z; }
        }
    }
}

extern "C" void kernel_launch(void* const* d_in, const int* in_sizes, int n_in,
                              void* d_out, int out_size, void* d_ws, size_t ws_size,
                              hipStream_t stream) {
    const float* x     = (const float*)d_in[0];
    const int*   ei    = (const int*)d_in[1];   // [2, E]
    const float* lin_w = (const float*)d_in[2]; // [OUT_CH, IN_CH]
    const float* lin_b = (const float*)d_in[3]; // [OUT_CH]
    const float* wts   = (const float*)d_in[4]; // [K]
    float* out = (float*)d_out;

    char* ws = (char*)d_ws;
    size_t off = 0;
    auto alloc = [&](size_t bytes) -> void* {
        void* p = ws + off;
        off += (bytes + 255) & ~(size_t)255;
        return p;
    };
    int*   meta     = (int*)  alloc((2 * N_NODES + 64) * 4); // deg + cursor + counter (one memset)
    int*   deg      = meta;
    int*   cursor   = meta + N_NODES;
    int*   counter  = meta + 2 * N_NODES;
    int*   seg_start= (int*)  alloc(N_NODES * 4);
    float* dinv     = (float*)alloc(N_NODES * 4);
    int*   csr_col  = (int*)  alloc((size_t)CSR_CAP * 4);
    float*          h0    = (float*)         alloc((size_t)N_NODES * OUT_CH * 4);
    unsigned short* h0b   = (unsigned short*)alloc((size_t)2 * (N_NODES + 1) * HALF_CH * 2);
    float*          out1  = (float*)         alloc((size_t)N_NODES * OUT_CH * 4);
    unsigned short* out1b = (unsigned short*)alloc((size_t)2 * (N_NODES + 1) * HALF_CH * 2);
    unsigned short* t2b   = (unsigned short*)alloc((size_t)2 * (N_NODES + 1) * HALF_CH * 2);

    hipMemsetAsync(meta, 0, (2 * N_NODES + 64) * 4, stream);

    const int* row = ei;
    const int* col = ei + E_EDGES;

    deg_kernel<<<(E_EDGES + 255) / 256, 256, 0, stream>>>(row, deg, E_EDGES);
    alloc_kernel<<<(N_NODES + 255) / 256, 256, 0, stream>>>(deg, seg_start, dinv, counter,
                                                            csr_col, N_NODES);

    // fused: GEMM (h0 fp32 + h0b bf16 planar pre-scaled) || CSR scatter
    gemm_scatter<<<G_GEMM + G_SCAT, 256, 0, stream>>>(x, lin_w, lin_b, dinv, h0, h0b,
                                                      row, col, seg_start, cursor, csr_col);

    int sgrid = (2 * N_NODES + 3) / 4; // 2 waves/node, 4 waves/block
    // out1 = h0 + w0 * spmm(h0)
    spmm_kernel<<<sgrid, 256, 0, stream>>>(h0b, seg_start, deg, csr_col, dinv, h0, wts, 0,
                                           nullptr, out1, out1b, N_NODES);
    // t2 = spmm(out1)
    spmm_kernel<<<sgrid, 256, 0, stream>>>(out1b, seg_start, deg, csr_col, dinv, nullptr, wts, 0,
                                           t2b, nullptr, nullptr, N_NODES);
    // out = out1 + w1 * spmm(t2)
    spmm_kernel<<<sgrid, 256, 0, stream>>>(t2b, seg_start, deg, csr_col, dinv, out1, wts, 1,
                                           nullptr, out, nullptr, N_NODES);
}

// Round 11
// 247.333 us; speedup vs baseline: 1.2073x; 1.0452x over previous
//
#include <hip/hip_runtime.h>

#define N_NODES 10000
#define E_EDGES 640000
#define IN_CH   512
#define OUT_CH  256
#define HALF_CH 128
#define CSR_CAP (E_EDGES + 16 * N_NODES + 128)  // padded capacity + prefetch slack
#define G_GEMM_X 157                            // ceil(10000/64)
#define G_GEMM  (G_GEMM_X * 2)                  // x2 planes
#define G_SCAT  625                             // 625*256*4 = 640000 edges

typedef short bf16x8 __attribute__((ext_vector_type(8)));
typedef float f32x4  __attribute__((ext_vector_type(4)));

__device__ __forceinline__ unsigned short f2b(float f) {
    unsigned int u = __float_as_uint(f);
    return (unsigned short)((u + 0x7FFFu + ((u >> 16) & 1u)) >> 16);
}
__device__ __forceinline__ float lo16(unsigned int u) { return __uint_as_float(u << 16); }
__device__ __forceinline__ float hi16(unsigned int u) { return __uint_as_float(u & 0xFFFF0000u); }

// ---------------- degree histogram (pure) ----------------
__global__ void deg_kernel(const int* __restrict__ row, int* __restrict__ deg, int E) {
    int e = blockIdx.x * blockDim.x + threadIdx.x;
    if (e < E) atomicAdd(&deg[row[e]], 1);
}

// ---------------- order-free segment allocation + dinv + pad-slot sentinels ----------------
__global__ void alloc_kernel(const int* __restrict__ deg, int* __restrict__ seg_start,
                             float* __restrict__ dinv, int* __restrict__ counter,
                             int* __restrict__ csr_col, int n) {
    int i = blockIdx.x * blockDim.x + threadIdx.x;
    if (i >= n) return;
    int d = deg[i];
    dinv[i] = (d > 0) ? rsqrtf((float)d) : 0.0f;
    int pad = (d + 15) & ~15;
    int s = atomicAdd(counter, pad);
    seg_start[i] = s;
    for (int j = d; j < pad; j++) csr_col[s + j] = N_NODES;
}

// ---------------- fused GEMM (blocks 0..G_GEMM-1) + edge scatter (rest) ----------------
__global__ __launch_bounds__(256) void gemm_scatter(const float* __restrict__ x,
                                                    const float* __restrict__ w,
                                                    const float* __restrict__ bias,
                                                    const float* __restrict__ dinv,
                                                    float* __restrict__ h0,
                                                    unsigned short* __restrict__ h0b,
                                                    const int* __restrict__ row,
                                                    const int* __restrict__ col,
                                                    const int* __restrict__ seg_start,
                                                    int* __restrict__ cursor,
                                                    int* __restrict__ csr_col) {
    __shared__ unsigned short As[64][72];
    __shared__ unsigned short Bs[128][72];
    int bid = blockIdx.x;
    int tid = threadIdx.x;
    if (bid >= G_GEMM) {
        // ---- scatter path ----
        int idx = (bid - G_GEMM) * 256 + tid;
        #pragma unroll
        for (int it = 0; it < 4; it++) {
            int e = idx + it * (G_SCAT * 256);
            if (e < E_EDGES) {
                int r = row[e];
                int c = col[e];
                int p = seg_start[r] + atomicAdd(&cursor[r], 1);
                csr_col[p] = c;
            }
        }
        return;
    }
    // ---- gemm path ----
    int bx = bid % G_GEMM_X;
    int plane = bid / G_GEMM_X;
    int wave = tid >> 6, lane = tid & 63, quad = lane >> 4, l16 = lane & 15;
    int row0 = bx * 64;
    int n0 = plane * 128;
    unsigned short* h0b_p = h0b + (size_t)plane * (N_NODES + 1) * HALF_CH;

    int ar = tid >> 2;
    int aseg = (tid & 3) * 16;
    int br = tid >> 1;
    int bseg = (tid & 1) * 32;

    f32x4 acc[8] = {};
    for (int k0 = 0; k0 < IN_CH; k0 += 64) {
        {
            int gr = row0 + ar;
            if (gr < N_NODES) {
                const float4* src = (const float4*)(x + (size_t)gr * IN_CH + k0 + aseg);
                #pragma unroll
                for (int i = 0; i < 4; i++) {
                    float4 v = src[i];
                    ushort4 o;
                    o.x = f2b(v.x); o.y = f2b(v.y); o.z = f2b(v.z); o.w = f2b(v.w);
                    *(ushort4*)&As[ar][aseg + i * 4] = o;
                }
            } else {
                ushort4 z = {0, 0, 0, 0};
                #pragma unroll
                for (int i = 0; i < 4; i++) *(ushort4*)&As[ar][aseg + i * 4] = z;
            }
        }
        {
            const float4* src = (const float4*)(w + (size_t)(n0 + br) * IN_CH + k0 + bseg);
            #pragma unroll
            for (int i = 0; i < 8; i++) {
                float4 v = src[i];
                ushort4 o;
                o.x = f2b(v.x); o.y = f2b(v.y); o.z = f2b(v.z); o.w = f2b(v.w);
                *(ushort4*)&Bs[br][bseg + i * 4] = o;
            }
        }
        __syncthreads();
        #pragma unroll
        for (int kk = 0; kk < 2; kk++) {
            bf16x8 a = *(const bf16x8*)&As[wave * 16 + l16][kk * 32 + quad * 8];
            #pragma unroll
            for (int t = 0; t < 8; t++) {
                bf16x8 b = *(const bf16x8*)&Bs[t * 16 + l16][kk * 32 + quad * 8];
                acc[t] = __builtin_amdgcn_mfma_f32_16x16x32_bf16(a, b, acc[t], 0, 0, 0);
            }
        }
        __syncthreads();
    }
    #pragma unroll
    for (int t = 0; t < 8; t++) {
        int lcol = t * 16 + l16;
        int col_ = n0 + lcol;
        float bv = bias[col_];
        #pragma unroll
        for (int r = 0; r < 4; r++) {
            int grow = row0 + wave * 16 + quad * 4 + r;
            if (grow < N_NODES) {
                float v = acc[t][r] + bv;
                h0   [(size_t)grow * OUT_CH + col_] = v;
                h0b_p[(size_t)grow * HALF_CH + lcol] = f2b(v * dinv[grow]);
            }
        }
    }
    // zero the pad row (sentinel gather target) — one block per plane
    if (bx == 0 && tid < 64)
        ((unsigned int*)(h0b_p + (size_t)N_NODES * HALF_CH))[tid] = 0u;
}

// ---------------- SpMM: 4 neighbor rows per VMEM instruction ----------
// 2 waves per node (one per 128-ch plane). sub = lane>>4 picks the edge within a quad,
// l16 = lane&15 picks 16B of the 256B row (8 channels). Per 16-edge group:
// 4 dwordx4 gathers + 4 broadcast col loads (+4 prefetch) vs 20 VMEM in the old scheme.
// End: shfl_xor(16,32) reduction over subs; sub-0 lanes run the epilogue.
__global__ __launch_bounds__(256) void spmm_kernel(const unsigned short* __restrict__ hb,
                                                   const int* __restrict__ seg_start,
                                                   const int* __restrict__ deg,
                                                   const int* __restrict__ csr_col,
                                                   const float* __restrict__ dinv,
                                                   const float* __restrict__ prev,
                                                   const float* __restrict__ wts, int widx,
                                                   unsigned short* __restrict__ yb_out,
                                                   float* __restrict__ axpy_out,
                                                   unsigned short* __restrict__ axpyb_out,
                                                   int n) {
    int W = (blockIdx.x * blockDim.x + threadIdx.x) >> 6;
    int lane = threadIdx.x & 63;
    int plane = (W >= n) ? 1 : 0;
    int node = W - plane * n;
    if (node >= n) return;
    int sub = lane >> 4, l16 = lane & 15;
    size_t pstride = (size_t)(n + 1) * HALF_CH;
    const unsigned short* hp = hb + (size_t)plane * pstride;

    int s = seg_start[node];
    int e = s + ((deg[node] + 15) & ~15);
    float acc[8] = {0.f, 0.f, 0.f, 0.f, 0.f, 0.f, 0.f, 0.f};
    if (s < e) {
        int c0 = csr_col[s + 0  + sub];
        int c1 = csr_col[s + 4  + sub];
        int c2 = csr_col[s + 8  + sub];
        int c3 = csr_col[s + 12 + sub];
        int p = s;
        while (true) {
            int pn = p + 16;
            int n0c = csr_col[pn + 0  + sub];   // prefetch next group's cols (slack-safe)
            int n1c = csr_col[pn + 4  + sub];
            int n2c = csr_col[pn + 8  + sub];
            int n3c = csr_col[pn + 12 + sub];
            uint4 v0 = *(const uint4*)(hp + (size_t)c0 * HALF_CH + l16 * 8);
            uint4 v1 = *(const uint4*)(hp + (size_t)c1 * HALF_CH + l16 * 8);
            uint4 v2 = *(const uint4*)(hp + (size_t)c2 * HALF_CH + l16 * 8);
            uint4 v3 = *(const uint4*)(hp + (size_t)c3 * HALF_CH + l16 * 8);
            acc[0] += lo16(v0.x) + lo16(v1.x) + lo16(v2.x) + lo16(v3.x);
            acc[1] += hi16(v0.x) + hi16(v1.x) + hi16(v2.x) + hi16(v3.x);
            acc[2] += lo16(v0.y) + lo16(v1.y) + lo16(v2.y) + lo16(v3.y);
            acc[3] += hi16(v0.y) + hi16(v1.y) + hi16(v2.y) + hi16(v3.y);
            acc[4] += lo16(v0.z) + lo16(v1.z) + lo16(v2.z) + lo16(v3.z);
            acc[5] += hi16(v0.z) + hi16(v1.z) + hi16(v2.z) + hi16(v3.z);
            acc[6] += lo16(v0.w) + lo16(v1.w) + lo16(v2.w) + lo16(v3.w);
            acc[7] += hi16(v0.w) + hi16(v1.w) + hi16(v2.w) + hi16(v3.w);
            c0 = n0c; c1 = n1c; c2 = n2c; c3 = n3c; p = pn;
            if (p >= e) break;
        }
    }
    // reduce across the 4 subs (lanes l16, l16+16, l16+32, l16+48)
    #pragma unroll
    for (int k = 0; k < 8; k++) {
        acc[k] += __shfl_xor(acc[k], 16, 64);
        acc[k] += __shfl_xor(acc[k], 32, 64);
    }
    if (sub != 0) return;

    float di = dinv[node];
    float y[8];
    #pragma unroll
    for (int k = 0; k < 8; k++) y[k] = di * acc[k];

    // lane l16 owns channels [l16*8, l16*8+8) within the plane
    size_t pbase = (size_t)plane * pstride + (size_t)node * HALF_CH + l16 * 8;
    size_t padrow = (size_t)plane * pstride + (size_t)n * HALF_CH + l16 * 8;
    if (yb_out) {
        ushort4 o0, o1;
        o0.x = f2b(di * y[0]); o0.y = f2b(di * y[1]); o0.z = f2b(di * y[2]); o0.w = f2b(di * y[3]);
        o1.x = f2b(di * y[4]); o1.y = f2b(di * y[5]); o1.z = f2b(di * y[6]); o1.w = f2b(di * y[7]);
        *(ushort4*)(yb_out + pbase) = o0;
        *(ushort4*)(yb_out + pbase + 4) = o1;
        if (node == 0) {
            ushort4 z = {0, 0, 0, 0};
            *(ushort4*)(yb_out + padrow) = z;
            *(ushort4*)(yb_out + padrow + 4) = z;
        }
    }
    if (axpy_out || axpyb_out) {
        float wk = wts[widx];
        size_t fbase = (size_t)node * OUT_CH + plane * HALF_CH + l16 * 8;
        float4 p0 = *(const float4*)(prev + fbase);
        float4 p1 = *(const float4*)(prev + fbase + 4);
        float4 o0, o1;
        o0.x = p0.x + wk * y[0]; o0.y = p0.y + wk * y[1];
        o0.z = p0.z + wk * y[2]; o0.w = p0.w + wk * y[3];
        o1.x = p1.x + wk * y[4]; o1.y = p1.y + wk * y[5];
        o1.z = p1.z + wk * y[6]; o1.w = p1.w + wk * y[7];
        if (axpy_out) {
            *(float4*)(axpy_out + fbase) = o0;
            *(float4*)(axpy_out + fbase + 4) = o1;
        }
        if (axpyb_out) {
            ushort4 b0, b1;
            b0.x = f2b(di * o0.x); b0.y = f2b(di * o0.y); b0.z = f2b(di * o0.z); b0.w = f2b(di * o0.w);
            b1.x = f2b(di * o1.x); b1.y = f2b(di * o1.y); b1.z = f2b(di * o1.z); b1.w = f2b(di * o1.w);
            *(ushort4*)(axpyb_out + pbase) = b0;
            *(ushort4*)(axpyb_out + pbase + 4) = b1;
            if (node == 0) {
                ushort4 z = {0, 0, 0, 0};
                *(ushort4*)(axpyb_out + padrow) = z;
                *(ushort4*)(axpyb_out + padrow + 4) = z;
            }
        }
    }
}

extern "C" void kernel_launch(void* const* d_in, const int* in_sizes, int n_in,
                              void* d_out, int out_size, void* d_ws, size_t ws_size,
                              hipStream_t stream) {
    const float* x     = (const float*)d_in[0];
    const int*   ei    = (const int*)d_in[1];   // [2, E]
    const float* lin_w = (const float*)d_in[2]; // [OUT_CH, IN_CH]
    const float* lin_b = (const float*)d_in[3]; // [OUT_CH]
    const float* wts   = (const float*)d_in[4]; // [K]
    float* out = (float*)d_out;

    char* ws = (char*)d_ws;
    size_t off = 0;
    auto alloc = [&](size_t bytes) -> void* {
        void* p = ws + off;
        off += (bytes + 255) & ~(size_t)255;
        return p;
    };
    int*   meta     = (int*)  alloc((2 * N_NODES + 64) * 4); // deg + cursor + counter
    int*   deg      = meta;
    int*   cursor   = meta + N_NODES;
    int*   counter  = meta + 2 * N_NODES;
    int*   seg_start= (int*)  alloc(N_NODES * 4);
    float* dinv     = (float*)alloc(N_NODES * 4);
    int*   csr_col  = (int*)  alloc((size_t)CSR_CAP * 4);
    float*          h0    = (float*)         alloc((size_t)N_NODES * OUT_CH * 4);
    unsigned short* h0b   = (unsigned short*)alloc((size_t)2 * (N_NODES + 1) * HALF_CH * 2);
    float*          out1  = (float*)         alloc((size_t)N_NODES * OUT_CH * 4);
    unsigned short* out1b = (unsigned short*)alloc((size_t)2 * (N_NODES + 1) * HALF_CH * 2);
    unsigned short* t2b   = (unsigned short*)alloc((size_t)2 * (N_NODES + 1) * HALF_CH * 2);

    hipMemsetAsync(meta, 0, (2 * N_NODES + 64) * 4, stream);

    const int* row = ei;
    const int* col = ei + E_EDGES;

    deg_kernel<<<(E_EDGES + 255) / 256, 256, 0, stream>>>(row, deg, E_EDGES);
    alloc_kernel<<<(N_NODES + 255) / 256, 256, 0, stream>>>(deg, seg_start, dinv, counter,
                                                            csr_col, N_NODES);

    // fused: GEMM (h0 fp32 + h0b bf16 planar pre-scaled) || CSR scatter
    gemm_scatter<<<G_GEMM + G_SCAT, 256, 0, stream>>>(x, lin_w, lin_b, dinv, h0, h0b,
                                                      row, col, seg_start, cursor, csr_col);

    int sgrid = (2 * N_NODES + 3) / 4; // 2 waves/node, 4 waves/block
    // out1 = h0 + w0 * spmm(h0)
    spmm_kernel<<<sgrid, 256, 0, stream>>>(h0b, seg_start, deg, csr_col, dinv, h0, wts, 0,
                                           nullptr, out1, out1b, N_NODES);
    // t2 = spmm(out1)
    spmm_kernel<<<sgrid, 256, 0, stream>>>(out1b, seg_start, deg, csr_col, dinv, nullptr, wts, 0,
                                           t2b, nullptr, nullptr, N_NODES);
    // out = out1 + w1 * spmm(t2)
    spmm_kernel<<<sgrid, 256, 0, stream>>>(t2b, seg_start, deg, csr_col, dinv, out1, wts, 1,
                                           nullptr, out, nullptr, N_NODES);
}

// Round 12
// 240.498 us; speedup vs baseline: 1.2416x; 1.0284x over previous
//
#include <hip/hip_runtime.h>

#define N_NODES 10000
#define E_EDGES 640000
#define IN_CH   512
#define OUT_CH  256
#define HALF_CH 128
#define CSR_CAP (E_EDGES + 16 * N_NODES + 128)  // padded capacity + prefetch slack
#define G_GEMM_X 157                            // ceil(10000/64)
#define G_GEMM  (G_GEMM_X * 2)                  // x2 planes
#define G_SCAT  2500                            // 2500*256 = 640000 edges, 1 edge/thread

typedef short bf16x8 __attribute__((ext_vector_type(8)));
typedef float f32x4  __attribute__((ext_vector_type(4)));

__device__ __forceinline__ unsigned short f2b(float f) {
    unsigned int u = __float_as_uint(f);
    return (unsigned short)((u + 0x7FFFu + ((u >> 16) & 1u)) >> 16);
}
__device__ __forceinline__ float lo16(unsigned int u) { return __uint_as_float(u << 16); }
__device__ __forceinline__ float hi16(unsigned int u) { return __uint_as_float(u & 0xFFFF0000u); }

// ---------------- degree histogram (pure) ----------------
__global__ void deg_kernel(const int* __restrict__ row, int* __restrict__ deg, int E) {
    int e = blockIdx.x * blockDim.x + threadIdx.x;
    if (e < E) atomicAdd(&deg[row[e]], 1);
}

// ---------------- order-free segment allocation + dinv + pad-slot sentinels ----------------
// cursor is line-padded (one int per 32-int cache line) and pre-loaded with seg_start so
// the scatter does a single atomicAdd per edge (no seg_start load, no false sharing).
__global__ void alloc_kernel(const int* __restrict__ deg, int* __restrict__ seg_start,
                             int* __restrict__ cursor32, float* __restrict__ dinv,
                             int* __restrict__ counter, int* __restrict__ csr_col, int n) {
    int i = blockIdx.x * blockDim.x + threadIdx.x;
    if (i >= n) return;
    int d = deg[i];
    dinv[i] = (d > 0) ? rsqrtf((float)d) : 0.0f;
    int pad = (d + 15) & ~15;
    int s = atomicAdd(counter, pad);
    seg_start[i] = s;
    cursor32[i << 5] = s;
    for (int j = d; j < pad; j++) csr_col[s + j] = N_NODES;
}

// ---------------- fused GEMM (blocks 0..G_GEMM-1) + edge scatter (rest) ----------------
__global__ __launch_bounds__(256) void gemm_scatter(const float* __restrict__ x,
                                                    const float* __restrict__ w,
                                                    const float* __restrict__ bias,
                                                    const float* __restrict__ dinv,
                                                    float* __restrict__ h0,
                                                    unsigned short* __restrict__ h0b,
                                                    const int* __restrict__ row,
                                                    const int* __restrict__ col,
                                                    int* __restrict__ cursor32,
                                                    int* __restrict__ csr_col) {
    __shared__ unsigned short As[64][72];
    __shared__ unsigned short Bs[128][72];
    int bid = blockIdx.x;
    int tid = threadIdx.x;
    if (bid >= G_GEMM) {
        // ---- scatter path: one edge per thread ----
        int e = (bid - G_GEMM) * 256 + tid;
        if (e < E_EDGES) {
            int r = row[e];
            int c = col[e];
            int p = atomicAdd(&cursor32[r << 5], 1);
            csr_col[p] = c;
        }
        return;
    }
    // ---- gemm path ----
    int bx = bid % G_GEMM_X;
    int plane = bid / G_GEMM_X;
    int wave = tid >> 6, lane = tid & 63, quad = lane >> 4, l16 = lane & 15;
    int row0 = bx * 64;
    int n0 = plane * 128;
    unsigned short* h0b_p = h0b + (size_t)plane * (N_NODES + 1) * HALF_CH;

    int ar = tid >> 2;
    int aseg = (tid & 3) * 16;
    int br = tid >> 1;
    int bseg = (tid & 1) * 32;

    f32x4 acc[8] = {};
    for (int k0 = 0; k0 < IN_CH; k0 += 64) {
        {
            int gr = row0 + ar;
            if (gr < N_NODES) {
                const float4* src = (const float4*)(x + (size_t)gr * IN_CH + k0 + aseg);
                #pragma unroll
                for (int i = 0; i < 4; i++) {
                    float4 v = src[i];
                    ushort4 o;
                    o.x = f2b(v.x); o.y = f2b(v.y); o.z = f2b(v.z); o.w = f2b(v.w);
                    *(ushort4*)&As[ar][aseg + i * 4] = o;
                }
            } else {
                ushort4 z = {0, 0, 0, 0};
                #pragma unroll
                for (int i = 0; i < 4; i++) *(ushort4*)&As[ar][aseg + i * 4] = z;
            }
        }
        {
            const float4* src = (const float4*)(w + (size_t)(n0 + br) * IN_CH + k0 + bseg);
            #pragma unroll
            for (int i = 0; i < 8; i++) {
                float4 v = src[i];
                ushort4 o;
                o.x = f2b(v.x); o.y = f2b(v.y); o.z = f2b(v.z); o.w = f2b(v.w);
                *(ushort4*)&Bs[br][bseg + i * 4] = o;
            }
        }
        __syncthreads();
        #pragma unroll
        for (int kk = 0; kk < 2; kk++) {
            bf16x8 a = *(const bf16x8*)&As[wave * 16 + l16][kk * 32 + quad * 8];
            #pragma unroll
            for (int t = 0; t < 8; t++) {
                bf16x8 b = *(const bf16x8*)&Bs[t * 16 + l16][kk * 32 + quad * 8];
                acc[t] = __builtin_amdgcn_mfma_f32_16x16x32_bf16(a, b, acc[t], 0, 0, 0);
            }
        }
        __syncthreads();
    }
    #pragma unroll
    for (int t = 0; t < 8; t++) {
        int lcol = t * 16 + l16;
        int col_ = n0 + lcol;
        float bv = bias[col_];
        #pragma unroll
        for (int r = 0; r < 4; r++) {
            int grow = row0 + wave * 16 + quad * 4 + r;
            if (grow < N_NODES) {
                float v = acc[t][r] + bv;
                h0   [(size_t)grow * OUT_CH + col_] = v;
                h0b_p[(size_t)grow * HALF_CH + lcol] = f2b(v * dinv[grow]);
            }
        }
    }
    // zero the pad row (sentinel gather target) — one block per plane
    if (bx == 0 && tid < 64)
        ((unsigned int*)(h0b_p + (size_t)N_NODES * HALF_CH))[tid] = 0u;
}

// ---------------- SpMM: 4 neighbor rows per VMEM instruction ----------
// 2 waves per node (one per 128-ch plane). sub = lane>>4 picks the edge within a quad,
// l16 = lane&15 picks 16B of the 256B row (8 channels). shfl_xor(16,32) final reduce.
__global__ __launch_bounds__(256) void spmm_kernel(const unsigned short* __restrict__ hb,
                                                   const int* __restrict__ seg_start,
                                                   const int* __restrict__ deg,
                                                   const int* __restrict__ csr_col,
                                                   const float* __restrict__ dinv,
                                                   const float* __restrict__ prev,
                                                   const float* __restrict__ wts, int widx,
                                                   unsigned short* __restrict__ yb_out,
                                                   float* __restrict__ axpy_out,
                                                   unsigned short* __restrict__ axpyb_out,
                                                   int n) {
    int W = (blockIdx.x * blockDim.x + threadIdx.x) >> 6;
    int lane = threadIdx.x & 63;
    int plane = (W >= n) ? 1 : 0;
    int node = W - plane * n;
    if (node >= n) return;
    int sub = lane >> 4, l16 = lane & 15;
    size_t pstride = (size_t)(n + 1) * HALF_CH;
    const unsigned short* hp = hb + (size_t)plane * pstride;

    int s = seg_start[node];
    int e = s + ((deg[node] + 15) & ~15);
    float acc[8] = {0.f, 0.f, 0.f, 0.f, 0.f, 0.f, 0.f, 0.f};
    if (s < e) {
        int c0 = csr_col[s + 0  + sub];
        int c1 = csr_col[s + 4  + sub];
        int c2 = csr_col[s + 8  + sub];
        int c3 = csr_col[s + 12 + sub];
        int p = s;
        while (true) {
            int pn = p + 16;
            int n0c = csr_col[pn + 0  + sub];   // prefetch next group's cols (slack-safe)
            int n1c = csr_col[pn + 4  + sub];
            int n2c = csr_col[pn + 8  + sub];
            int n3c = csr_col[pn + 12 + sub];
            uint4 v0 = *(const uint4*)(hp + (size_t)c0 * HALF_CH + l16 * 8);
            uint4 v1 = *(const uint4*)(hp + (size_t)c1 * HALF_CH + l16 * 8);
            uint4 v2 = *(const uint4*)(hp + (size_t)c2 * HALF_CH + l16 * 8);
            uint4 v3 = *(const uint4*)(hp + (size_t)c3 * HALF_CH + l16 * 8);
            acc[0] += lo16(v0.x) + lo16(v1.x) + lo16(v2.x) + lo16(v3.x);
            acc[1] += hi16(v0.x) + hi16(v1.x) + hi16(v2.x) + hi16(v3.x);
            acc[2] += lo16(v0.y) + lo16(v1.y) + lo16(v2.y) + lo16(v3.y);
            acc[3] += hi16(v0.y) + hi16(v1.y) + hi16(v2.y) + hi16(v3.y);
            acc[4] += lo16(v0.z) + lo16(v1.z) + lo16(v2.z) + lo16(v3.z);
            acc[5] += hi16(v0.z) + hi16(v1.z) + hi16(v2.z) + hi16(v3.z);
            acc[6] += lo16(v0.w) + lo16(v1.w) + lo16(v2.w) + lo16(v3.w);
            acc[7] += hi16(v0.w) + hi16(v1.w) + hi16(v2.w) + hi16(v3.w);
            c0 = n0c; c1 = n1c; c2 = n2c; c3 = n3c; p = pn;
            if (p >= e) break;
        }
    }
    #pragma unroll
    for (int k = 0; k < 8; k++) {
        acc[k] += __shfl_xor(acc[k], 16, 64);
        acc[k] += __shfl_xor(acc[k], 32, 64);
    }
    if (sub != 0) return;

    float di = dinv[node];
    float y[8];
    #pragma unroll
    for (int k = 0; k < 8; k++) y[k] = di * acc[k];

    size_t pbase = (size_t)plane * pstride + (size_t)node * HALF_CH + l16 * 8;
    size_t padrow = (size_t)plane * pstride + (size_t)n * HALF_CH + l16 * 8;
    if (yb_out) {
        ushort4 o0, o1;
        o0.x = f2b(di * y[0]); o0.y = f2b(di * y[1]); o0.z = f2b(di * y[2]); o0.w = f2b(di * y[3]);
        o1.x = f2b(di * y[4]); o1.y = f2b(di * y[5]); o1.z = f2b(di * y[6]); o1.w = f2b(di * y[7]);
        *(ushort4*)(yb_out + pbase) = o0;
        *(ushort4*)(yb_out + pbase + 4) = o1;
        if (node == 0) {
            ushort4 z = {0, 0, 0, 0};
            *(ushort4*)(yb_out + padrow) = z;
            *(ushort4*)(yb_out + padrow + 4) = z;
        }
    }
    if (axpy_out || axpyb_out) {
        float wk = wts[widx];
        size_t fbase = (size_t)node * OUT_CH + plane * HALF_CH + l16 * 8;
        float4 p0 = *(const float4*)(prev + fbase);
        float4 p1 = *(const float4*)(prev + fbase + 4);
        float4 o0, o1;
        o0.x = p0.x + wk * y[0]; o0.y = p0.y + wk * y[1];
        o0.z = p0.z + wk * y[2]; o0.w = p0.w + wk * y[3];
        o1.x = p1.x + wk * y[4]; o1.y = p1.y + wk * y[5];
        o1.z = p1.z + wk * y[6]; o1.w = p1.w + wk * y[7];
        if (axpy_out) {
            *(float4*)(axpy_out + fbase) = o0;
            *(float4*)(axpy_out + fbase + 4) = o1;
        }
        if (axpyb_out) {
            ushort4 b0, b1;
            b0.x = f2b(di * o0.x); b0.y = f2b(di * o0.y); b0.z = f2b(di * o0.z); b0.w = f2b(di * o0.w);
            b1.x = f2b(di * o1.x); b1.y = f2b(di * o1.y); b1.z = f2b(di * o1.z); b1.w = f2b(di * o1.w);
            *(ushort4*)(axpyb_out + pbase) = b0;
            *(ushort4*)(axpyb_out + pbase + 4) = b1;
            if (node == 0) {
                ushort4 z = {0, 0, 0, 0};
                *(ushort4*)(axpyb_out + padrow) = z;
                *(ushort4*)(axpyb_out + padrow + 4) = z;
            }
        }
    }
}

extern "C" void kernel_launch(void* const* d_in, const int* in_sizes, int n_in,
                              void* d_out, int out_size, void* d_ws, size_t ws_size,
                              hipStream_t stream) {
    const float* x     = (const float*)d_in[0];
    const int*   ei    = (const int*)d_in[1];   // [2, E]
    const float* lin_w = (const float*)d_in[2]; // [OUT_CH, IN_CH]
    const float* lin_b = (const float*)d_in[3]; // [OUT_CH]
    const float* wts   = (const float*)d_in[4]; // [K]
    float* out = (float*)d_out;

    char* ws = (char*)d_ws;
    size_t off = 0;
    auto alloc = [&](size_t bytes) -> void* {
        void* p = ws + off;
        off += (bytes + 255) & ~(size_t)255;
        return p;
    };
    int*   meta     = (int*)  alloc((N_NODES + 64) * 4);     // deg + counter (one memset)
    int*   deg      = meta;
    int*   counter  = meta + N_NODES;
    int*   cursor32 = (int*)  alloc((size_t)N_NODES * 32 * 4); // line-padded cursors
    int*   seg_start= (int*)  alloc(N_NODES * 4);
    float* dinv     = (float*)alloc(N_NODES * 4);
    int*   csr_col  = (int*)  alloc((size_t)CSR_CAP * 4);
    float*          h0    = (float*)         alloc((size_t)N_NODES * OUT_CH * 4);
    unsigned short* h0b   = (unsigned short*)alloc((size_t)2 * (N_NODES + 1) * HALF_CH * 2);
    float*          out1  = (float*)         alloc((size_t)N_NODES * OUT_CH * 4);
    unsigned short* out1b = (unsigned short*)alloc((size_t)2 * (N_NODES + 1) * HALF_CH * 2);
    unsigned short* t2b   = (unsigned short*)alloc((size_t)2 * (N_NODES + 1) * HALF_CH * 2);

    hipMemsetAsync(meta, 0, (N_NODES + 64) * 4, stream);

    const int* row = ei;
    const int* col = ei + E_EDGES;

    deg_kernel<<<(E_EDGES + 255) / 256, 256, 0, stream>>>(row, deg, E_EDGES);
    alloc_kernel<<<(N_NODES + 255) / 256, 256, 0, stream>>>(deg, seg_start, cursor32, dinv,
                                                            counter, csr_col, N_NODES);

    // fused: GEMM (h0 fp32 + h0b bf16 planar pre-scaled) || CSR scatter
    gemm_scatter<<<G_GEMM + G_SCAT, 256, 0, stream>>>(x, lin_w, lin_b, dinv, h0, h0b,
                                                      row, col, cursor32, csr_col);

    int sgrid = (2 * N_NODES + 3) / 4; // 2 waves/node, 4 waves/block
    // out1 = h0 + w0 * spmm(h0)
    spmm_kernel<<<sgrid, 256, 0, stream>>>(h0b, seg_start, deg, csr_col, dinv, h0, wts, 0,
                                           nullptr, out1, out1b, N_NODES);
    // t2 = spmm(out1)
    spmm_kernel<<<sgrid, 256, 0, stream>>>(out1b, seg_start, deg, csr_col, dinv, nullptr, wts, 0,
                                           t2b, nullptr, nullptr, N_NODES);
    // out = out1 + w1 * spmm(t2)
    spmm_kernel<<<sgrid, 256, 0, stream>>>(t2b, seg_start, deg, csr_col, dinv, out1, wts, 1,
                                           nullptr, out, nullptr, N_NODES);
}

// Round 13
// 238.480 us; speedup vs baseline: 1.2521x; 1.0085x over previous
//
#include <hip/hip_runtime.h>

#define N_NODES 10000
#define E_EDGES 640000
#define IN_CH   512
#define OUT_CH  256
#define HALF_CH 128
#define CSR_CAP (E_EDGES + 16 * N_NODES + 128)  // padded capacity + prefetch slack
#define G_GEMM_X 157                            // ceil(10000/64)
#define G_GEMM  (G_GEMM_X * 2)                  // x2 planes
#define G_SCAT  2500                            // 2500*256 = 640000 edges, 1 edge/thread

typedef short bf16x8 __attribute__((ext_vector_type(8)));
typedef float f32x4  __attribute__((ext_vector_type(4)));

__device__ __forceinline__ unsigned short f2b(float f) {
    unsigned int u = __float_as_uint(f);
    return (unsigned short)((u + 0x7FFFu + ((u >> 16) & 1u)) >> 16);
}
__device__ __forceinline__ float lo16(unsigned int u) { return __uint_as_float(u << 16); }
__device__ __forceinline__ float hi16(unsigned int u) { return __uint_as_float(u & 0xFFFF0000u); }
__device__ __forceinline__ float b2f(unsigned short u) { return __uint_as_float(((unsigned int)u) << 16); }

// ---------------- degree histogram (pure) ----------------
__global__ void deg_kernel(const int* __restrict__ row, int* __restrict__ deg, int E) {
    int e = blockIdx.x * blockDim.x + threadIdx.x;
    if (e < E) atomicAdd(&deg[row[e]], 1);
}

// ---------------- order-free segment allocation + dinv/sq + pad-slot sentinels ----------------
// cursor line-padded & pre-loaded with seg_start: scatter = single atomicAdd per edge.
// sq[i] = sqrt(deg) lets spmm reconstruct unscaled features from dinv-pre-scaled bf16.
__global__ void alloc_kernel(const int* __restrict__ deg, int* __restrict__ seg_start,
                             int* __restrict__ cursor32, float* __restrict__ dinv,
                             float* __restrict__ sq, int* __restrict__ counter,
                             int* __restrict__ csr_col, int n) {
    int i = blockIdx.x * blockDim.x + threadIdx.x;
    if (i >= n) return;
    int d = deg[i];
    dinv[i] = (d > 0) ? rsqrtf((float)d) : 0.0f;
    sq[i]   = (d > 0) ? sqrtf((float)d) : 0.0f;
    int pad = (d + 15) & ~15;
    int s = atomicAdd(counter, pad);
    seg_start[i] = s;
    cursor32[i << 5] = s;
    for (int j = d; j < pad; j++) csr_col[s + j] = N_NODES;
}

// ---------------- fused GEMM (blocks 0..G_GEMM-1) + edge scatter (rest) ----------------
// GEMM writes ONLY bf16 planar h0b pre-scaled by dinv[m] (no fp32 copy — spmm reconstructs).
__global__ __launch_bounds__(256) void gemm_scatter(const float* __restrict__ x,
                                                    const float* __restrict__ w,
                                                    const float* __restrict__ bias,
                                                    const float* __restrict__ dinv,
                                                    unsigned short* __restrict__ h0b,
                                                    const int* __restrict__ row,
                                                    const int* __restrict__ col,
                                                    int* __restrict__ cursor32,
                                                    int* __restrict__ csr_col) {
    __shared__ unsigned short As[64][72];
    __shared__ unsigned short Bs[128][72];
    int bid = blockIdx.x;
    int tid = threadIdx.x;
    if (bid >= G_GEMM) {
        // ---- scatter path: one edge per thread ----
        int e = (bid - G_GEMM) * 256 + tid;
        if (e < E_EDGES) {
            int r = row[e];
            int c = col[e];
            int p = atomicAdd(&cursor32[r << 5], 1);
            csr_col[p] = c;
        }
        return;
    }
    // ---- gemm path ----
    int bx = bid % G_GEMM_X;
    int plane = bid / G_GEMM_X;
    int wave = tid >> 6, lane = tid & 63, quad = lane >> 4, l16 = lane & 15;
    int row0 = bx * 64;
    int n0 = plane * 128;
    unsigned short* h0b_p = h0b + (size_t)plane * (N_NODES + 1) * HALF_CH;

    int ar = tid >> 2;
    int aseg = (tid & 3) * 16;
    int br = tid >> 1;
    int bseg = (tid & 1) * 32;

    f32x4 acc[8] = {};
    for (int k0 = 0; k0 < IN_CH; k0 += 64) {
        {
            int gr = row0 + ar;
            if (gr < N_NODES) {
                const float4* src = (const float4*)(x + (size_t)gr * IN_CH + k0 + aseg);
                #pragma unroll
                for (int i = 0; i < 4; i++) {
                    float4 v = src[i];
                    ushort4 o;
                    o.x = f2b(v.x); o.y = f2b(v.y); o.z = f2b(v.z); o.w = f2b(v.w);
                    *(ushort4*)&As[ar][aseg + i * 4] = o;
                }
            } else {
                ushort4 z = {0, 0, 0, 0};
                #pragma unroll
                for (int i = 0; i < 4; i++) *(ushort4*)&As[ar][aseg + i * 4] = z;
            }
        }
        {
            const float4* src = (const float4*)(w + (size_t)(n0 + br) * IN_CH + k0 + bseg);
            #pragma unroll
            for (int i = 0; i < 8; i++) {
                float4 v = src[i];
                ushort4 o;
                o.x = f2b(v.x); o.y = f2b(v.y); o.z = f2b(v.z); o.w = f2b(v.w);
                *(ushort4*)&Bs[br][bseg + i * 4] = o;
            }
        }
        __syncthreads();
        #pragma unroll
        for (int kk = 0; kk < 2; kk++) {
            bf16x8 a = *(const bf16x8*)&As[wave * 16 + l16][kk * 32 + quad * 8];
            #pragma unroll
            for (int t = 0; t < 8; t++) {
                bf16x8 b = *(const bf16x8*)&Bs[t * 16 + l16][kk * 32 + quad * 8];
                acc[t] = __builtin_amdgcn_mfma_f32_16x16x32_bf16(a, b, acc[t], 0, 0, 0);
            }
        }
        __syncthreads();
    }
    #pragma unroll
    for (int t = 0; t < 8; t++) {
        int lcol = t * 16 + l16;
        int col_ = n0 + lcol;
        float bv = bias[col_];
        #pragma unroll
        for (int r = 0; r < 4; r++) {
            int grow = row0 + wave * 16 + quad * 4 + r;
            if (grow < N_NODES) {
                float v = acc[t][r] + bv;
                h0b_p[(size_t)grow * HALF_CH + lcol] = f2b(v * dinv[grow]);
            }
        }
    }
    // zero the pad row (sentinel gather target) — one block per plane
    if (bx == 0 && tid < 64)
        ((unsigned int*)(h0b_p + (size_t)N_NODES * HALF_CH))[tid] = 0u;
}

// ---------------- SpMM: 4 neighbor rows per VMEM instruction ----------
// 2 waves per node (one per 128-ch plane). sub picks the edge in a quad, l16 picks 16B of
// the row. prev is reconstructed from dinv-pre-scaled bf16: prev = b2f(prev_b) * sq[node].
__global__ __launch_bounds__(256) void spmm_kernel(const unsigned short* __restrict__ hb,
                                                   const int* __restrict__ seg_start,
                                                   const int* __restrict__ deg,
                                                   const int* __restrict__ csr_col,
                                                   const float* __restrict__ dinv,
                                                   const float* __restrict__ sq,
                                                   const unsigned short* __restrict__ prev_b,
                                                   const float* __restrict__ wts, int widx,
                                                   unsigned short* __restrict__ yb_out,
                                                   float* __restrict__ axpy_out,
                                                   unsigned short* __restrict__ axpyb_out,
                                                   int n) {
    int W = (blockIdx.x * blockDim.x + threadIdx.x) >> 6;
    int lane = threadIdx.x & 63;
    int plane = (W >= n) ? 1 : 0;
    int node = W - plane * n;
    if (node >= n) return;
    int sub = lane >> 4, l16 = lane & 15;
    size_t pstride = (size_t)(n + 1) * HALF_CH;
    const unsigned short* hp = hb + (size_t)plane * pstride;

    int s = seg_start[node];
    int e = s + ((deg[node] + 15) & ~15);
    float acc[8] = {0.f, 0.f, 0.f, 0.f, 0.f, 0.f, 0.f, 0.f};
    if (s < e) {
        int c0 = csr_col[s + 0  + sub];
        int c1 = csr_col[s + 4  + sub];
        int c2 = csr_col[s + 8  + sub];
        int c3 = csr_col[s + 12 + sub];
        int p = s;
        while (true) {
            int pn = p + 16;
            int n0c = csr_col[pn + 0  + sub];   // prefetch next group's cols (slack-safe)
            int n1c = csr_col[pn + 4  + sub];
            int n2c = csr_col[pn + 8  + sub];
            int n3c = csr_col[pn + 12 + sub];
            uint4 v0 = *(const uint4*)(hp + (size_t)c0 * HALF_CH + l16 * 8);
            uint4 v1 = *(const uint4*)(hp + (size_t)c1 * HALF_CH + l16 * 8);
            uint4 v2 = *(const uint4*)(hp + (size_t)c2 * HALF_CH + l16 * 8);
            uint4 v3 = *(const uint4*)(hp + (size_t)c3 * HALF_CH + l16 * 8);
            acc[0] += lo16(v0.x) + lo16(v1.x) + lo16(v2.x) + lo16(v3.x);
            acc[1] += hi16(v0.x) + hi16(v1.x) + hi16(v2.x) + hi16(v3.x);
            acc[2] += lo16(v0.y) + lo16(v1.y) + lo16(v2.y) + lo16(v3.y);
            acc[3] += hi16(v0.y) + hi16(v1.y) + hi16(v2.y) + hi16(v3.y);
            acc[4] += lo16(v0.z) + lo16(v1.z) + lo16(v2.z) + lo16(v3.z);
            acc[5] += hi16(v0.z) + hi16(v1.z) + hi16(v2.z) + hi16(v3.z);
            acc[6] += lo16(v0.w) + lo16(v1.w) + lo16(v2.w) + lo16(v3.w);
            acc[7] += hi16(v0.w) + hi16(v1.w) + hi16(v2.w) + hi16(v3.w);
            c0 = n0c; c1 = n1c; c2 = n2c; c3 = n3c; p = pn;
            if (p >= e) break;
        }
    }
    #pragma unroll
    for (int k = 0; k < 8; k++) {
        acc[k] += __shfl_xor(acc[k], 16, 64);
        acc[k] += __shfl_xor(acc[k], 32, 64);
    }
    if (sub != 0) return;

    float di = dinv[node];
    float y[8];
    #pragma unroll
    for (int k = 0; k < 8; k++) y[k] = di * acc[k];

    size_t pbase = (size_t)plane * pstride + (size_t)node * HALF_CH + l16 * 8;
    size_t padrow = (size_t)plane * pstride + (size_t)n * HALF_CH + l16 * 8;
    if (yb_out) {
        ushort4 o0, o1;
        o0.x = f2b(di * y[0]); o0.y = f2b(di * y[1]); o0.z = f2b(di * y[2]); o0.w = f2b(di * y[3]);
        o1.x = f2b(di * y[4]); o1.y = f2b(di * y[5]); o1.z = f2b(di * y[6]); o1.w = f2b(di * y[7]);
        *(ushort4*)(yb_out + pbase) = o0;
        *(ushort4*)(yb_out + pbase + 4) = o1;
        if (node == 0) {
            ushort4 z = {0, 0, 0, 0};
            *(ushort4*)(yb_out + padrow) = z;
            *(ushort4*)(yb_out + padrow + 4) = z;
        }
    }
    if (prev_b) {
        float wk = wts[widx];
        float sqn = sq[node];
        ushort4 p0 = *(const ushort4*)(prev_b + pbase);
        ushort4 p1 = *(const ushort4*)(prev_b + pbase + 4);
        float o[8];
        o[0] = b2f(p0.x) * sqn + wk * y[0];
        o[1] = b2f(p0.y) * sqn + wk * y[1];
        o[2] = b2f(p0.z) * sqn + wk * y[2];
        o[3] = b2f(p0.w) * sqn + wk * y[3];
        o[4] = b2f(p1.x) * sqn + wk * y[4];
        o[5] = b2f(p1.y) * sqn + wk * y[5];
        o[6] = b2f(p1.z) * sqn + wk * y[6];
        o[7] = b2f(p1.w) * sqn + wk * y[7];
        if (axpy_out) {
            size_t fbase = (size_t)node * OUT_CH + plane * HALF_CH + l16 * 8;
            float4 f0 = {o[0], o[1], o[2], o[3]};
            float4 f1 = {o[4], o[5], o[6], o[7]};
            *(float4*)(axpy_out + fbase) = f0;
            *(float4*)(axpy_out + fbase + 4) = f1;
        }
        if (axpyb_out) {
            ushort4 b0, b1;
            b0.x = f2b(di * o[0]); b0.y = f2b(di * o[1]); b0.z = f2b(di * o[2]); b0.w = f2b(di * o[3]);
            b1.x = f2b(di * o[4]); b1.y = f2b(di * o[5]); b1.z = f2b(di * o[6]); b1.w = f2b(di * o[7]);
            *(ushort4*)(axpyb_out + pbase) = b0;
            *(ushort4*)(axpyb_out + pbase + 4) = b1;
            if (node == 0) {
                ushort4 z = {0, 0, 0, 0};
                *(ushort4*)(axpyb_out + padrow) = z;
                *(ushort4*)(axpyb_out + padrow + 4) = z;
            }
        }
    }
}

extern "C" void kernel_launch(void* const* d_in, const int* in_sizes, int n_in,
                              void* d_out, int out_size, void* d_ws, size_t ws_size,
                              hipStream_t stream) {
    const float* x     = (const float*)d_in[0];
    const int*   ei    = (const int*)d_in[1];   // [2, E]
    const float* lin_w = (const float*)d_in[2]; // [OUT_CH, IN_CH]
    const float* lin_b = (const float*)d_in[3]; // [OUT_CH]
    const float* wts   = (const float*)d_in[4]; // [K]
    float* out = (float*)d_out;

    char* ws = (char*)d_ws;
    size_t off = 0;
    auto alloc = [&](size_t bytes) -> void* {
        void* p = ws + off;
        off += (bytes + 255) & ~(size_t)255;
        return p;
    };
    int*   meta     = (int*)  alloc((N_NODES + 64) * 4);       // deg + counter (one memset)
    int*   deg      = meta;
    int*   counter  = meta + N_NODES;
    int*   cursor32 = (int*)  alloc((size_t)N_NODES * 32 * 4); // line-padded cursors
    int*   seg_start= (int*)  alloc(N_NODES * 4);
    float* dinv     = (float*)alloc(N_NODES * 4);
    float* sq       = (float*)alloc(N_NODES * 4);
    int*   csr_col  = (int*)  alloc((size_t)CSR_CAP * 4);
    unsigned short* h0b   = (unsigned short*)alloc((size_t)2 * (N_NODES + 1) * HALF_CH * 2);
    unsigned short* out1b = (unsigned short*)alloc((size_t)2 * (N_NODES + 1) * HALF_CH * 2);
    unsigned short* t2b   = (unsigned short*)alloc((size_t)2 * (N_NODES + 1) * HALF_CH * 2);

    hipMemsetAsync(meta, 0, (N_NODES + 64) * 4, stream);

    const int* row = ei;
    const int* col = ei + E_EDGES;

    deg_kernel<<<(E_EDGES + 255) / 256, 256, 0, stream>>>(row, deg, E_EDGES);
    alloc_kernel<<<(N_NODES + 255) / 256, 256, 0, stream>>>(deg, seg_start, cursor32, dinv,
                                                            sq, counter, csr_col, N_NODES);

    // fused: GEMM (h0b bf16 planar pre-scaled only) || CSR scatter
    gemm_scatter<<<G_GEMM + G_SCAT, 256, 0, stream>>>(x, lin_w, lin_b, dinv, h0b,
                                                      row, col, cursor32, csr_col);

    int sgrid = (2 * N_NODES + 3) / 4; // 2 waves/node, 4 waves/block
    // out1b = dinv*(h0 + w0 * spmm(h0)), h0 reconstructed from h0b
    spmm_kernel<<<sgrid, 256, 0, stream>>>(h0b, seg_start, deg, csr_col, dinv, sq, h0b,
                                           wts, 0, nullptr, nullptr, out1b, N_NODES);
    // t2b = dinv*spmm(out1)
    spmm_kernel<<<sgrid, 256, 0, stream>>>(out1b, seg_start, deg, csr_col, dinv, sq, nullptr,
                                           wts, 0, t2b, nullptr, nullptr, N_NODES);
    // out = out1 + w1 * spmm(t2), out1 reconstructed from out1b  (fp32 final)
    spmm_kernel<<<sgrid, 256, 0, stream>>>(t2b, seg_start, deg, csr_col, dinv, sq, out1b,
                                           wts, 1, nullptr, out, nullptr, N_NODES);
}